// Round 10
// baseline (45.449 us; speedup 1.0000x reference)
//
#include <hip/hip_runtime.h>
#include <hip/hip_bf16.h>

#define EPS 1e-5f

typedef __attribute__((ext_vector_type(8))) short bf16x8;
typedef __attribute__((ext_vector_type(4))) float f32x4;
typedef unsigned short ushort_t;
#define MFMA16(a, b, c) __builtin_amdgcn_mfma_f32_16x16x32_bf16(a, b, c, 0, 0, 0)

// ---- ws layout ----
// f32  [0..143]    YT[k][c] conv1 weights (k-major, 16ch each)
// f32  [144..367]  consts: a1[16] c1[16] a2[32] c2[32] a3[64] c3[64]
// bf16 half-index 1024:  W2F  2mt*5ks*64lane*8  = 5120
// bf16 half-index 6144:  W3F  4mt*9ks*64*8      = 18432
// bf16 half-index 24576: WFC1F 8mt*18ks*64*8    = 73728  (pos-major k!)
#define CST_OFF  144
#define W2F_H    1024
#define W3F_H    6144
#define WFC1F_H  24576
#define PREP_ITEMS (368 + 5120 + 18432 + 73728)

__device__ __forceinline__ unsigned short f2bf(float f) {
    unsigned int u = __builtin_bit_cast(unsigned int, f);
    return (unsigned short)((u + 0x7fffu + ((u >> 16) & 1u)) >> 16);
}

__global__ __launch_bounds__(256) void prep_kernel(
    const int* __restrict__ y_int,
    const float* __restrict__ w2, const float* __restrict__ w3,
    const float* __restrict__ wfc1,
    const float* __restrict__ bias1,
    const float* __restrict__ g1, const float* __restrict__ b1,
    const float* __restrict__ m1, const float* __restrict__ v1,
    const float* __restrict__ g2, const float* __restrict__ b2,
    const float* __restrict__ m2, const float* __restrict__ v2,
    const float* __restrict__ bias2,
    const float* __restrict__ g3, const float* __restrict__ b3,
    const float* __restrict__ m3, const float* __restrict__ v3,
    const float* __restrict__ bias3,
    float* __restrict__ ws)
{
    unsigned short* wsh = (unsigned short*)ws;
    int i = blockIdx.x * 256 + threadIdx.x;
    if (i < 144) {
        int k = i >> 4, c = i & 15;
        ws[i] = (float)y_int[c * 9 + k];
    } else if (i < 368) {
        int idx = i - 144;
        if (idx < 16) { int c = idx;
            ws[CST_OFF + idx] = g1[c] * rsqrtf(v1[c] + EPS) * 1e-4f;
        } else if (idx < 32) { int c = idx - 16;
            float inv = g1[c] * rsqrtf(v1[c] + EPS);
            ws[CST_OFF + idx] = bias1[c] * inv + b1[c] - m1[c] * inv;
        } else if (idx < 64) { int c = idx - 32;
            ws[CST_OFF + idx] = g2[c] * rsqrtf(v2[c] + EPS);
        } else if (idx < 96) { int c = idx - 64;
            float inv = g2[c] * rsqrtf(v2[c] + EPS);
            ws[CST_OFF + idx] = bias2[c] * inv + b2[c] - m2[c] * inv;
        } else if (idx < 160) { int c = idx - 96;
            ws[CST_OFF + idx] = g3[c] * rsqrtf(v3[c] + EPS);
        } else { int c = idx - 160;
            float inv = g3[c] * rsqrtf(v3[c] + EPS);
            ws[CST_OFF + idx] = bias3[c] * inv + b3[c] - m3[c] * inv;
        }
    } else {
        int e = i - 368;
        if (e < 5120) {
            int m = e / 2560, r = e % 2560, s = r >> 9, l = (r >> 3) & 63, j = e & 7;
            int kl  = ((l >> 4) << 3) + j;
            int tap = 2 * s + (kl >> 4), ci = kl & 15;
            int ch  = m * 16 + (l & 15);
            float v = (tap < 9) ? w2[ch * 144 + ci * 9 + tap] : 0.f;
            wsh[W2F_H + e] = f2bf(v);
        } else if (e < 5120 + 18432) {
            int e3 = e - 5120;
            int mt = e3 / 4608, r = e3 % 4608, ks = r >> 9, l = (r >> 3) & 63, j = e3 & 7;
            int ch = mt * 16 + (l & 15), ci = ((l >> 4) << 3) + j;
            wsh[W3F_H + e3] = f2bf(w3[ch * 288 + ci * 9 + ks]);
        } else {
            int ef = e - 23552;
            int mt = ef / 9216, r = ef % 9216, ks = r >> 9, l = (r >> 3) & 63, j = ef & 7;
            int ch = mt * 16 + (l & 15);
            int kp = ks * 32 + ((l >> 4) << 3) + j;     // pos-major k index
            int ci = kp & 63, pos = kp >> 6;
            wsh[WFC1F_H + ef] = f2bf(wfc1[ch * 576 + ci * 9 + pos]);
        }
    }
}

// ONE image per block, 3 waves (192 thr), ONE barrier.
// Wave t owns conv3 pre-pool rows {2t,2t+1}: loads its own image rows ->
// its F1 rows -> its F2 rows -> conv3 -> FC1 partial on its own k-slices
// (pos-major FLAT: wave w's FC1 slice reads only positions wave w wrote).
// Per-wave 10080B: IMG 22x30 f32 | F1 2 planes x 10 rows x 256B | F2 2304B.
__global__ __launch_bounds__(192, 3) void fused_cnn(
    const int* __restrict__ x_img,
    const float* __restrict__ ws,
    const float* __restrict__ bfc1,
    const float* __restrict__ wfc2, const float* __restrict__ bfc2,
    float* __restrict__ out)
{
    const int tid  = threadIdx.x;
    const int lane = tid & 63;
    const int wv   = __builtin_amdgcn_readfirstlane(tid >> 6);  // 0..2 = t-group
    const int img  = blockIdx.x;
    const unsigned short* wsh = (const unsigned short*)ws;

    __shared__ __align__(16) char s_all[32928];
    char*     W    = s_all + wv * 10080;
    float*    IMG  = (float*)W;                   // [22][30] f32
    char*     F1w  = W + 2640;                    // 2 planes x 10 rows x 256B
    char*     F2w  = W + 7760;                    // 4 q x 4 rows x 9 pos x 16B
    ushort_t* FLAT = (ushort_t*)(s_all + 30240);  // [9 pos][64 ch]
    float*    Hp   = (float*)(s_all + 31392);     // [3][128]

    // wave-role constants (halo-audited)
    const int F0  = (wv == 0) ? 0 : (wv == 1) ? 2 : 6;    // first padded F1 row in frame
    const int I0  = (wv == 0) ? 0 : (wv == 1) ? 2 : 10;   // first padded img row in frame
    const int PR0 = (wv == 0) ? 0 : (wv == 1) ? 1 : 5;    // first F1 content row computed
    const int NQ  = (wv == 0) ? 98 : (wv == 1) ? 140 : 126; // conv1 quads = rows*14
    const int PX0 = (wv == 0) ? 0 : (wv == 1) ? 1 : 9;    // first pixel row loaded
    const int NPX = (wv == 0) ? 15 : (wv == 1) ? 22 : 19; // pixel rows loaded
    const int PS  = (wv == 0) ? 0 : (wv == 1) ? 1 : 3;    // first conv2 p
    const int PC  = (wv == 0) ? 3 : 4;                    // conv2 p count
    const int LR0 = (wv == 0) ? -1 : (wv == 1) ? 1 : 3;   // F2 local row = p - LR0

    // ---- zero private region (630 uint4 = 10080B) ----
    {
        uint4 z = make_uint4(0u, 0u, 0u, 0u);
        uint4* zp = (uint4*)W;
        for (int j = lane; j < 630; j += 64) zp[j] = z;
    }
    // ---- load this wave's image rows ----
    const int* xp = x_img + img * 784;
    for (int j = lane; j < NPX * 28; j += 64) {
        int rr = j / 28, cc = j - rr * 28;
        IMG[(PX0 + rr + 1 - I0) * 30 + 1 + cc] = (float)xp[(PX0 + rr) * 28 + cc];
    }

    // ---- conv1 (fp32 exact) for this wave's F1 rows ----
    for (int q = lane; q < NQ; q += 64) {
        int pr = PR0 + q / 14, pw = q % 14;
        float acc[16][4];
        #pragma unroll
        for (int c = 0; c < 16; c++) {
            acc[c][0] = 0.f; acc[c][1] = 0.f; acc[c][2] = 0.f; acc[c][3] = 0.f;
        }
        const float* imgq = IMG + (2 * pr - I0) * 30 + pw * 2;
        #pragma unroll
        for (int k = 0; k < 9; k++) {
            const float* ip = imgq + (k / 3) * 30 + (k % 3);
            float x0 = ip[0], x1 = ip[1], x2 = ip[30], x3 = ip[31];
            const float4* yw = (const float4*)(ws + k * 16);
            float4 wA = yw[0], wB = yw[1], wC = yw[2], wD = yw[3];
            float wr[16] = {wA.x, wA.y, wA.z, wA.w, wB.x, wB.y, wB.z, wB.w,
                            wC.x, wC.y, wC.z, wC.w, wD.x, wD.y, wD.z, wD.w};
            #pragma unroll
            for (int c = 0; c < 16; c++) {
                float w = wr[c];
                acc[c][0] += w * x0; acc[c][1] += w * x1;
                acc[c][2] += w * x2; acc[c][3] += w * x3;
            }
        }
        unsigned int pk[8];
        #pragma unroll
        for (int c = 0; c < 16; c += 2) {
            float mx0 = fmaxf(fmaxf(acc[c][0], acc[c][1]), fmaxf(acc[c][2], acc[c][3]));
            float r0  = fmaxf(mx0 * ws[CST_OFF + c] + ws[CST_OFF + 16 + c], 0.f);
            float mx1 = fmaxf(fmaxf(acc[c+1][0], acc[c+1][1]), fmaxf(acc[c+1][2], acc[c+1][3]));
            float r1  = fmaxf(mx1 * ws[CST_OFF + c + 1] + ws[CST_OFF + 16 + c + 1], 0.f);
            pk[c >> 1] = (unsigned int)f2bf(r0) | ((unsigned int)f2bf(r1) << 16);
        }
        int L = pr + 1 - F0;                       // local padded row, 0..9
        *(uint4*)(F1w + L * 256 + (pw + 1) * 16)        = make_uint4(pk[0], pk[1], pk[2], pk[3]);
        *(uint4*)(F1w + 2560 + L * 256 + (pw + 1) * 16) = make_uint4(pk[4], pk[5], pk[6], pk[7]);
    }

    // ---- conv2 via MFMA for this wave's p-set -> private F2 ----
    {
        const int x = lane & 15, g = lane >> 4;
        const int t2 = g >> 1, c0 = g & 1;
        bf16x8 A2[2][5];
        #pragma unroll
        for (int m = 0; m < 2; m++)
            #pragma unroll
            for (int s = 0; s < 5; s++)
                A2[m][s] = *(const bf16x8*)(const void*)(wsh + W2F_H + ((m * 5 + s) * 64 + lane) * 8);
        int voff[5];
        #pragma unroll
        for (int s = 0; s < 5; s++) {
            int tap = 2 * s + t2;
            int dy = (tap < 9) ? tap / 3 : 0, dx = (tap < 9) ? tap % 3 : 0;
            voff[s] = c0 * 2560 + (dy * 16 + x + dx) * 16;   // plane 2560B, row 256B
        }
        float a2v[2][4], c2v[2][4];
        #pragma unroll
        for (int m = 0; m < 2; m++)
            #pragma unroll
            for (int r = 0; r < 4; r++) {
                int ch = m * 16 + g * 4 + r;
                a2v[m][r] = ws[CST_OFF + 32 + ch];
                c2v[m][r] = ws[CST_OFF + 64 + ch];
            }
        for (int i = 0; i < PC; i++) {
            int p = PS + i;
            const char* bp = F1w + (2 * p - F0) * 256;
            bf16x8 B0[5], B1[5];
            #pragma unroll
            for (int s = 0; s < 5; s++) {
                B0[s] = *(const bf16x8*)(const void*)(bp + voff[s]);
                B1[s] = *(const bf16x8*)(const void*)(bp + 256 + voff[s]);
            }
            #pragma unroll
            for (int m = 0; m < 2; m++) {
                f32x4 a0 = {0.f, 0.f, 0.f, 0.f}, a1 = {0.f, 0.f, 0.f, 0.f};
                #pragma unroll
                for (int s = 0; s < 5; s++) {
                    a0 = MFMA16(A2[m][s], B0[s], a0);
                    a1 = MFMA16(A2[m][s], B1[s], a1);
                }
                float hp[4];
                #pragma unroll
                for (int r = 0; r < 4; r++) {
                    float vp = fmaxf(a0[r], a1[r]);
                    hp[r] = fmaxf(vp, __shfl_xor(vp, 1));
                }
                if (!(x & 1) && x < 14) {
                    int xp2 = x >> 1;
                    int lrow = p - LR0;
                    int ch0 = m * 16 + g * 4;
                    unsigned int lo = (unsigned int)f2bf(fmaxf(hp[0] * a2v[m][0] + c2v[m][0], 0.f)) |
                                      ((unsigned int)f2bf(fmaxf(hp[1] * a2v[m][1] + c2v[m][1], 0.f)) << 16);
                    unsigned int hi = (unsigned int)f2bf(fmaxf(hp[2] * a2v[m][2] + c2v[m][2], 0.f)) |
                                      ((unsigned int)f2bf(fmaxf(hp[3] * a2v[m][3] + c2v[m][3], 0.f)) << 16);
                    *(uint2*)(F2w + (ch0 >> 3) * 576 + (lrow * 9 + xp2 + 1) * 16 + (ch0 & 7) * 2) = make_uint2(lo, hi);
                }
            }
        }
    }

    // ---- conv3 via MFMA (this wave's t, all 64 ch) -> FLAT (pos-major) ----
    {
        const int x8 = lane & 7, ry = (lane >> 3) & 1, qg = lane >> 4;
        bf16x8 bb[9];
        #pragma unroll
        for (int ks = 0; ks < 9; ks++) {
            int dy = ks / 3, dx = ks % 3;
            bb[ks] = *(const bf16x8*)(const void*)(F2w + qg * 576 + ((ry + dy) * 9 + x8 + dx) * 16);
        }
        #pragma unroll
        for (int mt = 0; mt < 4; mt++) {
            bf16x8 A3[9];
            #pragma unroll
            for (int ks = 0; ks < 9; ks++)
                A3[ks] = *(const bf16x8*)(const void*)(wsh + W3F_H + ((mt * 9 + ks) * 64 + lane) * 8);
            f32x4 acc = {0.f, 0.f, 0.f, 0.f};
            #pragma unroll
            for (int ks = 0; ks < 9; ks++)
                acc = MFMA16(A3[ks], bb[ks], acc);
            float hp[4];
            #pragma unroll
            for (int r = 0; r < 4; r++) {
                float vp = fmaxf(acc[r], __shfl_xor(acc[r], 8));
                hp[r] = fmaxf(vp, __shfl_xor(vp, 1));
            }
            if (ry == 0 && !(x8 & 1) && x8 < 6) {
                int xp3 = x8 >> 1;
                int ch0 = mt * 16 + qg * 4;
                #pragma unroll
                for (int r = 0; r < 4; r++) {
                    float a3 = ws[CST_OFF + 96 + ch0 + r];
                    float c3 = ws[CST_OFF + 160 + ch0 + r];
                    float v = fmaxf(hp[r] * a3 + c3, 0.f);
                    FLAT[(wv * 3 + xp3) * 64 + ch0 + r] = f2bf(v);
                }
            }
        }
    }

    // ---- FC1 partial via MFMA: this wave's 6 k-slices (its own FLAT rows) ----
    {
        const int g = lane >> 4;
        f32x4 acc8[8];
        #pragma unroll
        for (int mt = 0; mt < 8; mt++) acc8[mt] = (f32x4){0.f, 0.f, 0.f, 0.f};
        #pragma unroll
        for (int mt = 0; mt < 8; mt++) {
            #pragma unroll
            for (int ksl = 0; ksl < 6; ksl++) {
                int ks = wv * 6 + ksl;
                bf16x8 a  = *(const bf16x8*)(const void*)(wsh + WFC1F_H + ((mt * 18 + ks) * 64 + lane) * 8);
                bf16x8 bv = *(const bf16x8*)(const void*)(FLAT + ks * 32 + g * 8);
                acc8[mt] = MFMA16(a, bv, acc8[mt]);
            }
        }
        if ((lane & 15) == 0) {
            #pragma unroll
            for (int mt = 0; mt < 8; mt++)
                #pragma unroll
                for (int r = 0; r < 4; r++)
                    Hp[wv * 128 + mt * 16 + g * 4 + r] = acc8[mt][r];
        }
    }
    __syncthreads();

    // ---- FC2 (wave 0): combine partials, relu, 10 outputs ----
    if (wv == 0) {
        int ch = lane * 2;
        float h0 = fmaxf(Hp[ch]     + Hp[128 + ch]     + Hp[256 + ch]     + bfc1[ch],     0.f);
        float h1 = fmaxf(Hp[ch + 1] + Hp[128 + ch + 1] + Hp[256 + ch + 1] + bfc1[ch + 1], 0.f);
        #pragma unroll
        for (int o = 0; o < 10; o++) {
            float a = wfc2[o * 128 + ch] * h0 + wfc2[o * 128 + ch + 1] * h1;
            a += __shfl_xor(a, 32);
            a += __shfl_xor(a, 16);
            a += __shfl_xor(a, 8);
            a += __shfl_xor(a, 4);
            a += __shfl_xor(a, 2);
            a += __shfl_xor(a, 1);
            if (lane == 0) out[img * 10 + o] = a + bfc2[o];
        }
    }
}

extern "C" void kernel_launch(void* const* d_in, const int* in_sizes, int n_in,
                              void* d_out, int out_size, void* d_ws, size_t ws_size,
                              hipStream_t stream) {
    float* ws = (float*)d_ws;
    prep_kernel<<<(PREP_ITEMS + 255) / 256, 256, 0, stream>>>(
        (const int*)d_in[1],                        // y_int
        (const float*)d_in[15],                     // w2
        (const float*)d_in[17],                     // w3
        (const float*)d_in[19],                     // w_fc1
        (const float*)d_in[2],                      // bias1
        (const float*)d_in[3], (const float*)d_in[4], (const float*)d_in[5], (const float*)d_in[6],
        (const float*)d_in[7], (const float*)d_in[8], (const float*)d_in[9], (const float*)d_in[10],
        (const float*)d_in[16],                     // bias2
        (const float*)d_in[11], (const float*)d_in[12], (const float*)d_in[13], (const float*)d_in[14],
        (const float*)d_in[18],                     // bias3
        ws);
    fused_cnn<<<1024, 192, 0, stream>>>(
        (const int*)d_in[0],                        // x_img
        ws,
        (const float*)d_in[20],                     // b_fc1
        (const float*)d_in[21], (const float*)d_in[22],  // w_fc2, b_fc2
        (float*)d_out);
}

// Round 11
// 27.162 us; speedup vs baseline: 1.6732x; 1.6732x over previous
//
#include <hip/hip_runtime.h>
#include <hip/hip_bf16.h>

#define EPS 1e-5f

typedef __attribute__((ext_vector_type(8))) short bf16x8;
typedef __attribute__((ext_vector_type(4))) float f32x4;
typedef unsigned short ushort_t;
#define MFMA16(a, b, c) __builtin_amdgcn_mfma_f32_16x16x32_bf16(a, b, c, 0, 0, 0)

// ---- ws layout ----
// f32  [0..143]    YT[k][c] conv1 weights (k-major, 16ch each)
// f32  [144..367]  consts: a1[16] c1[16] a2[32] c2[32] a3[64] c3[64]
// bf16 half-index 1024:  W2F  2mt*5ks*64lane*8  = 5120
// bf16 half-index 6144:  W3F  4mt*9ks*64*8      = 18432
// bf16 half-index 24576: WFC1F 8mt*20ks*64*8    = 81920
//   FC1 k' layout: k' in [0,640); wave w owns k' in [160w,160w+160):
//   lk = k'%160; lk<144 -> real k = (16w + lk/9)*9 + lk%9 (ci*9+pos); else 0-pad.
#define CST_OFF  144
#define W2F_H    1024
#define W3F_H    6144
#define WFC1F_H  24576
#define PREP_ITEMS (368 + 5120 + 18432 + 81920)

__device__ __forceinline__ unsigned short f2bf(float f) {
    unsigned int u = __builtin_bit_cast(unsigned int, f);
    return (unsigned short)((u + 0x7fffu + ((u >> 16) & 1u)) >> 16);
}

__global__ __launch_bounds__(256) void prep_kernel(
    const int* __restrict__ y_int,
    const float* __restrict__ w2, const float* __restrict__ w3,
    const float* __restrict__ wfc1,
    const float* __restrict__ bias1,
    const float* __restrict__ g1, const float* __restrict__ b1,
    const float* __restrict__ m1, const float* __restrict__ v1,
    const float* __restrict__ g2, const float* __restrict__ b2,
    const float* __restrict__ m2, const float* __restrict__ v2,
    const float* __restrict__ bias2,
    const float* __restrict__ g3, const float* __restrict__ b3,
    const float* __restrict__ m3, const float* __restrict__ v3,
    const float* __restrict__ bias3,
    float* __restrict__ ws)
{
    unsigned short* wsh = (unsigned short*)ws;
    int i = blockIdx.x * 256 + threadIdx.x;
    if (i < 144) {
        int k = i >> 4, c = i & 15;
        ws[i] = (float)y_int[c * 9 + k];
    } else if (i < 368) {
        int idx = i - 144;
        if (idx < 16) { int c = idx;
            ws[CST_OFF + idx] = g1[c] * rsqrtf(v1[c] + EPS) * 1e-4f;
        } else if (idx < 32) { int c = idx - 16;
            float inv = g1[c] * rsqrtf(v1[c] + EPS);
            ws[CST_OFF + idx] = bias1[c] * inv + b1[c] - m1[c] * inv;
        } else if (idx < 64) { int c = idx - 32;
            ws[CST_OFF + idx] = g2[c] * rsqrtf(v2[c] + EPS);
        } else if (idx < 96) { int c = idx - 64;
            float inv = g2[c] * rsqrtf(v2[c] + EPS);
            ws[CST_OFF + idx] = bias2[c] * inv + b2[c] - m2[c] * inv;
        } else if (idx < 160) { int c = idx - 96;
            ws[CST_OFF + idx] = g3[c] * rsqrtf(v3[c] + EPS);
        } else { int c = idx - 160;
            float inv = g3[c] * rsqrtf(v3[c] + EPS);
            ws[CST_OFF + idx] = bias3[c] * inv + b3[c] - m3[c] * inv;
        }
    } else {
        int e = i - 368;
        if (e < 5120) {
            int m = e / 2560, r = e % 2560, s = r >> 9, l = (r >> 3) & 63, j = e & 7;
            int kl  = ((l >> 4) << 3) + j;
            int tap = 2 * s + (kl >> 4), ci = kl & 15;
            int ch  = m * 16 + (l & 15);
            float v = (tap < 9) ? w2[ch * 144 + ci * 9 + tap] : 0.f;
            wsh[W2F_H + e] = f2bf(v);
        } else if (e < 5120 + 18432) {
            int e3 = e - 5120;
            int mt = e3 / 4608, r = e3 % 4608, ks = r >> 9, l = (r >> 3) & 63, j = e3 & 7;
            int ch = mt * 16 + (l & 15), ci = ((l >> 4) << 3) + j;
            wsh[W3F_H + e3] = f2bf(w3[ch * 288 + ci * 9 + ks]);
        } else {
            int ef = e - 23552;                          // [0, 81920)
            int mt = ef / 10240, r = ef % 10240;
            int ks = r >> 9, l = (r >> 3) & 63, j = ef & 7;
            int ch = mt * 16 + (l & 15);
            int kp = ks * 32 + ((l >> 4) << 3) + j;      // k' in [0,640)
            int w  = kp / 160, lk = kp - w * 160;
            float v = 0.f;
            if (lk < 144) v = wfc1[ch * 576 + (w * 16 + lk / 9) * 9 + (lk % 9)];
            wsh[WFC1F_H + ef] = f2bf(v);
        }
    }
}

// 1 image per block (256 thr, 4 waves), 1024 blocks, THREE barriers.
// Phase A: border-zero F1/F2 || conv1 reading pixels DIRECT from global.
// Phase B: conv2 (MFMA).  Phase C: conv3 (MFMA) -> FLAT (wave-local k'-region)
// -> FC1 partial (MFMA, own region, NO barrier).  Phase D: FC2 combine.
// LDS: F1 8192B ([2 c0][256 pos][8ch] bf16) + F2 5184B ([4 q][81 pos][8ch]).
// FLAT[640] bf16 + Hp[4][128] f32 alias F1 after conv2.
__global__ __launch_bounds__(256, 4) void fused_cnn(
    const int* __restrict__ x_img,
    const float* __restrict__ ws,
    const float* __restrict__ bfc1,
    const float* __restrict__ wfc2, const float* __restrict__ bfc2,
    float* __restrict__ out)
{
    const int tid  = threadIdx.x;
    const int lane = tid & 63;
    const int wv   = __builtin_amdgcn_readfirstlane(tid >> 6);  // 0..3
    const int img  = blockIdx.x;
    const unsigned short* wsh = (const unsigned short*)ws;

    __shared__ __align__(16) char s_f1[8192];
    __shared__ __align__(16) char s_f2[5184];
    ushort_t* FLAT = (ushort_t*)s_f1;             // 640 bf16 (1280B)
    float*    Hp   = (float*)(s_f1 + 1536);       // [4][128] f32

    // ---- phase A: border-zero (disjoint from conv1/conv2 writes) ----
    {
        uint4 z = make_uint4(0u, 0u, 0u, 0u);
        if (tid < 120) {
            int c0 = tid / 60, b = tid % 60, pos;
            if (b < 16)      pos = b;                    // row 0
            else if (b < 32) pos = 240 + (b - 16);       // row 15
            else if (b < 46) pos = (b - 31) * 16;        // col 0, rows 1..14
            else             pos = (b - 45) * 16 + 15;   // col 15
            *(uint4*)(s_f1 + c0 * 4096 + pos * 16) = z;
        } else if (tid < 248) {
            int zz = tid - 120;
            int q = zz / 32, b = zz % 32, pos;
            if (b < 9)       pos = b;                    // row 0
            else if (b < 18) pos = 72 + (b - 9);         // row 8
            else if (b < 25) pos = (b - 17) * 9;         // col 0, rows 1..7
            else             pos = (b - 24) * 9 + 8;     // col 8
            *(uint4*)(s_f2 + q * 1296 + pos * 16) = z;
        }
    }

    // ---- conv1 (fp32 exact), pixels straight from global ----
    if (tid < 196) {
        int ph = tid / 14, pw = tid - (tid / 14) * 14;
        const int* xp = x_img + img * 784;
        int ry0 = 2 * ph - 1, cx0 = 2 * pw - 1;
        float px[4][4];
        #pragma unroll
        for (int dy = 0; dy < 4; dy++) {
            int ry = ry0 + dy;
            int ryc = min(max(ry, 0), 27);
            bool rok = (unsigned)ry < 28u;
            #pragma unroll
            for (int dx = 0; dx < 4; dx++) {
                int cx = cx0 + dx;
                int cxc = min(max(cx, 0), 27);
                float v = (float)xp[ryc * 28 + cxc];
                px[dy][dx] = (rok && (unsigned)cx < 28u) ? v : 0.f;
            }
        }
        float acc[16][4];
        #pragma unroll
        for (int c = 0; c < 16; c++) {
            acc[c][0] = 0.f; acc[c][1] = 0.f; acc[c][2] = 0.f; acc[c][3] = 0.f;
        }
        #pragma unroll
        for (int k = 0; k < 9; k++) {
            int ty = k / 3, tx = k % 3;
            float x0 = px[ty][tx],     x1 = px[ty][tx + 1];
            float x2 = px[ty + 1][tx], x3 = px[ty + 1][tx + 1];
            const float4* yw = (const float4*)(ws + k * 16);
            float4 wA = yw[0], wB = yw[1], wC = yw[2], wD = yw[3];
            float wr[16] = {wA.x, wA.y, wA.z, wA.w, wB.x, wB.y, wB.z, wB.w,
                            wC.x, wC.y, wC.z, wC.w, wD.x, wD.y, wD.z, wD.w};
            #pragma unroll
            for (int c = 0; c < 16; c++) {
                float w = wr[c];
                acc[c][0] += w * x0; acc[c][1] += w * x1;
                acc[c][2] += w * x2; acc[c][3] += w * x3;
            }
        }
        unsigned int pk[8];
        #pragma unroll
        for (int c = 0; c < 16; c += 2) {
            float mx0 = fmaxf(fmaxf(acc[c][0], acc[c][1]), fmaxf(acc[c][2], acc[c][3]));
            float r0  = fmaxf(mx0 * ws[CST_OFF + c] + ws[CST_OFF + 16 + c], 0.f);
            float mx1 = fmaxf(fmaxf(acc[c+1][0], acc[c+1][1]), fmaxf(acc[c+1][2], acc[c+1][3]));
            float r1  = fmaxf(mx1 * ws[CST_OFF + c + 1] + ws[CST_OFF + 16 + c + 1], 0.f);
            pk[c >> 1] = (unsigned int)f2bf(r0) | ((unsigned int)f2bf(r1) << 16);
        }
        int pos = (ph + 1) * 16 + (pw + 1);
        *(uint4*)(s_f1 + pos * 16)        = make_uint4(pk[0], pk[1], pk[2], pk[3]);
        *(uint4*)(s_f1 + 4096 + pos * 16) = make_uint4(pk[4], pk[5], pk[6], pk[7]);
    }
    __syncthreads();   // bar 1: F1 ready

    // ---- phase B: conv2 via MFMA, rows p in {wv, wv+4} ----
    {
        const int x = lane & 15, g = lane >> 4;
        const int t2 = g >> 1, c0 = g & 1;
        bf16x8 A2[2][5];
        #pragma unroll
        for (int m = 0; m < 2; m++)
            #pragma unroll
            for (int s = 0; s < 5; s++)
                A2[m][s] = *(const bf16x8*)(const void*)(wsh + W2F_H + ((m * 5 + s) * 64 + lane) * 8);
        int voff[5];
        #pragma unroll
        for (int s = 0; s < 5; s++) {
            int tap = 2 * s + t2;
            int dy = (tap < 9) ? tap / 3 : 0, dx = (tap < 9) ? tap % 3 : 0;
            voff[s] = c0 * 4096 + (dy * 16 + x + dx) * 16;
        }
        float a2v[2][4], c2v[2][4];
        #pragma unroll
        for (int m = 0; m < 2; m++)
            #pragma unroll
            for (int r = 0; r < 4; r++) {
                int ch = m * 16 + g * 4 + r;
                a2v[m][r] = ws[CST_OFF + 32 + ch];
                c2v[m][r] = ws[CST_OFF + 64 + ch];
            }
        for (int p = wv; p < 7; p += 4) {
            const char* bp = s_f1 + p * 512;
            bf16x8 B0[5], B1[5];
            #pragma unroll
            for (int s = 0; s < 5; s++) {
                B0[s] = *(const bf16x8*)(const void*)(bp + voff[s]);
                B1[s] = *(const bf16x8*)(const void*)(bp + 256 + voff[s]);
            }
            #pragma unroll
            for (int m = 0; m < 2; m++) {
                f32x4 a0 = {0.f, 0.f, 0.f, 0.f}, a1 = {0.f, 0.f, 0.f, 0.f};
                #pragma unroll
                for (int s = 0; s < 5; s++) {
                    a0 = MFMA16(A2[m][s], B0[s], a0);
                    a1 = MFMA16(A2[m][s], B1[s], a1);
                }
                float hp[4];
                #pragma unroll
                for (int r = 0; r < 4; r++) {
                    float vp = fmaxf(a0[r], a1[r]);
                    hp[r] = fmaxf(vp, __shfl_xor(vp, 1));
                }
                if (!(x & 1) && x < 14) {
                    int xp2 = x >> 1;
                    int pp  = (p + 1) * 9 + xp2 + 1;
                    int ch0 = m * 16 + g * 4;
                    unsigned int lo = (unsigned int)f2bf(fmaxf(hp[0] * a2v[m][0] + c2v[m][0], 0.f)) |
                                      ((unsigned int)f2bf(fmaxf(hp[1] * a2v[m][1] + c2v[m][1], 0.f)) << 16);
                    unsigned int hi = (unsigned int)f2bf(fmaxf(hp[2] * a2v[m][2] + c2v[m][2], 0.f)) |
                                      ((unsigned int)f2bf(fmaxf(hp[3] * a2v[m][3] + c2v[m][3], 0.f)) << 16);
                    *(uint2*)(s_f2 + (ch0 >> 3) * 1296 + pp * 16 + (ch0 & 7) * 2) = make_uint2(lo, hi);
                }
            }
        }
    }
    __syncthreads();   // bar 2: F2 ready (F1 now dead -> FLAT/Hp scratch)

    // ---- phase C: conv3 (mt = wv) -> FLAT[wv*160..] -> FC1 partial, no barrier ----
    {
        const int mt = wv;
        bf16x8 A3[9];
        #pragma unroll
        for (int ks = 0; ks < 9; ks++)
            A3[ks] = *(const bf16x8*)(const void*)(wsh + W3F_H + ((mt * 9 + ks) * 64 + lane) * 8);
        const int x8 = lane & 7, ry = (lane >> 3) & 1, qg = lane >> 4;
        int voff3[9];
        #pragma unroll
        for (int ks = 0; ks < 9; ks++) {
            int dy = ks / 3, dx = ks % 3;
            voff3[ks] = qg * 1296 + ((ry + dy) * 9 + x8 + dx) * 16;
        }
        float a3v[4], c3v[4];
        #pragma unroll
        for (int r = 0; r < 4; r++) {
            int ch = mt * 16 + qg * 4 + r;
            a3v[r] = ws[CST_OFF + 96 + ch];
            c3v[r] = ws[CST_OFF + 160 + ch];
        }
        if (lane < 16) FLAT[wv * 160 + 144 + lane] = 0;   // zero-pad own k'-region
        #pragma unroll
        for (int t = 0; t < 3; t++) {
            bf16x8 bb[9];
            #pragma unroll
            for (int ks = 0; ks < 9; ks++)
                bb[ks] = *(const bf16x8*)(const void*)(s_f2 + t * 288 + voff3[ks]);
            f32x4 acc = {0.f, 0.f, 0.f, 0.f};
            #pragma unroll
            for (int ks = 0; ks < 9; ks++)
                acc = MFMA16(A3[ks], bb[ks], acc);
            float hp[4];
            #pragma unroll
            for (int r = 0; r < 4; r++) {
                float vp = fmaxf(acc[r], __shfl_xor(acc[r], 8));
                hp[r] = fmaxf(vp, __shfl_xor(vp, 1));
            }
            if (ry == 0 && !(x8 & 1) && x8 < 6) {
                int xp3 = x8 >> 1;
                #pragma unroll
                for (int r = 0; r < 4; r++) {
                    float v = fmaxf(hp[r] * a3v[r] + c3v[r], 0.f);
                    FLAT[wv * 160 + (qg * 4 + r) * 9 + t * 3 + xp3] = f2bf(v);
                }
            }
        }

        // FC1 partial: own k'-slices ks = 5wv..5wv+4, all 8 mt (B hoisted)
        const int g = lane >> 4;
        bf16x8 BV[5];
        #pragma unroll
        for (int ksl = 0; ksl < 5; ksl++)
            BV[ksl] = *(const bf16x8*)(const void*)(FLAT + (wv * 5 + ksl) * 32 + g * 8);
        #pragma unroll
        for (int mtf = 0; mtf < 8; mtf++) {
            f32x4 acc = {0.f, 0.f, 0.f, 0.f};
            #pragma unroll
            for (int ksl = 0; ksl < 5; ksl++) {
                int ks = wv * 5 + ksl;
                bf16x8 a = *(const bf16x8*)(const void*)(wsh + WFC1F_H + ((mtf * 20 + ks) * 64 + lane) * 8);
                acc = MFMA16(a, BV[ksl], acc);
            }
            if ((lane & 15) == 0) {
                int ch0 = mtf * 16 + g * 4;
                #pragma unroll
                for (int r = 0; r < 4; r++)
                    Hp[wv * 128 + ch0 + r] = acc[r];
            }
        }
    }
    __syncthreads();   // bar 3: Hp ready

    // ---- phase D: FC2, combine 4 partials ----
    if (tid < 160) {
        int o = tid / 16, l = tid & 15;
        float a = 0.f;
        #pragma unroll
        for (int k = l; k < 128; k += 16) {
            float h = Hp[k] + Hp[128 + k] + Hp[256 + k] + Hp[384 + k] + bfc1[k];
            h = fmaxf(h, 0.f);
            a += h * wfc2[o * 128 + k];
        }
        a += __shfl_xor(a, 8);
        a += __shfl_xor(a, 4);
        a += __shfl_xor(a, 2);
        a += __shfl_xor(a, 1);
        if (l == 0) out[img * 10 + o] = a + bfc2[o];
    }
}

extern "C" void kernel_launch(void* const* d_in, const int* in_sizes, int n_in,
                              void* d_out, int out_size, void* d_ws, size_t ws_size,
                              hipStream_t stream) {
    float* ws = (float*)d_ws;
    prep_kernel<<<(PREP_ITEMS + 255) / 256, 256, 0, stream>>>(
        (const int*)d_in[1],                        // y_int
        (const float*)d_in[15],                     // w2
        (const float*)d_in[17],                     // w3
        (const float*)d_in[19],                     // w_fc1
        (const float*)d_in[2],                      // bias1
        (const float*)d_in[3], (const float*)d_in[4], (const float*)d_in[5], (const float*)d_in[6],
        (const float*)d_in[7], (const float*)d_in[8], (const float*)d_in[9], (const float*)d_in[10],
        (const float*)d_in[16],                     // bias2
        (const float*)d_in[11], (const float*)d_in[12], (const float*)d_in[13], (const float*)d_in[14],
        (const float*)d_in[18],                     // bias3
        ws);
    fused_cnn<<<1024, 256, 0, stream>>>(
        (const int*)d_in[0],                        // x_img
        ws,
        (const float*)d_in[20],                     // b_fc1
        (const float*)d_in[21], (const float*)d_in[22],  // w_fc2, b_fc2
        (float*)d_out);
}